// Round 6
// baseline (981.838 us; speedup 1.0000x reference)
//
#include <hip/hip_runtime.h>
#include <hip/hip_bf16.h>

#define NNODE 100000
#define EDG   500000
#define NCLS  5

// ws layout (ushort units). All weights bf16 row-major with OUTPUT ROWS
// permuted by pi(); k-dims natural (pi makes produced-layout == consumed-
// layout, see pi() note). Biases fp32, pi-permuted.
#define OFF_W1   0                       // [128][64]
#define OFF_W2   8192                    // [128][128]
#define OFF_W3   24576
#define OFF_WCR  40960
#define OFF_WCL  57344
#define OFF_P0   73728
#define OFF_P1   90112
#define OFF_BIAS 106496                  // 384 fp32 (768 ushorts): b1,b2,b3
#define OFF_HU   (106496 + 768)          // [NNODE][128] bf16, pi-slot order
#define OFF_HV   (OFF_HU + NNODE * 128)
#define W_ELEMS  106496
#define B_ELEMS  384

typedef __attribute__((ext_vector_type(8))) short short8;
typedef __attribute__((ext_vector_type(4))) float f32x4;

__device__ __forceinline__ float bf2f(ushort u) {
  return __uint_as_float(((unsigned int)u) << 16);
}
__device__ __forceinline__ ushort f2bf(float f) {
  unsigned int u = __float_as_uint(f);
  u += 0x7FFF + ((u >> 16) & 1);
  return (ushort)(u >> 16);
}
__device__ __forceinline__ ushort2 pk2(float a, float b) {
  __hip_bfloat162 t = __float22bfloat162_rn(make_float2(a, b));
  return *(ushort2*)&t;
}

// pi: acc-slot p = mt*16+q*4+r  ->  semantic feature ks*32+q*8+j with
// mt=2ks+(j>>2), r=j&3. With weight rows stored in pi order, the MFMA C/D
// output IS the next GEMM's B-fragment (same lane), k-dims stay natural.
__device__ __forceinline__ int piperm(int p) {
  return (p >> 5) * 32 + ((p >> 2) & 3) * 8 + ((p >> 4) & 1) * 4 + (p & 3);
}

__device__ __forceinline__ short8 pkfrag(f32x4 lo, f32x4 hi) {
  union { short8 v; ushort2 h[4]; } o;
  o.h[0] = pk2(lo[0], lo[1]); o.h[1] = pk2(lo[2], lo[3]);
  o.h[2] = pk2(hi[0], hi[1]); o.h[3] = pk2(hi[2], hi[3]);
  return o.v;
}

__device__ __forceinline__ void zero8(f32x4 a[8]) {
#pragma unroll
  for (int i = 0; i < 8; ++i) a[i] = (f32x4){0.f, 0.f, 0.f, 0.f};
}

// Per-wave GEMM: acc[mt] (+)= W[mt-tile] * bf[ks]; wave = 16 edges, all 128
// out-feats. A-frags from global (L1/L2-hot), B-frags in registers.
template <int KS>
__device__ __forceinline__ void gemmW(const ushort* __restrict__ W, int K,
                                      const short8 bf[KS], f32x4 acc[8],
                                      int l15, int q) {
#pragma unroll
  for (int ks = 0; ks < KS; ++ks) {
#pragma unroll
    for (int mt = 0; mt < 8; ++mt) {
      short8 a = *(const short8*)(W + (mt * 16 + l15) * K + ks * 32 + q * 8);
      acc[mt] = __builtin_amdgcn_mfma_f32_16x16x32_bf16(a, bf[ks], acc[mt], 0, 0, 0);
    }
  }
}

// acc -> next-layer B-frags (pure register op thanks to pi).
__device__ __forceinline__ void mkfrags(const f32x4 acc[8],
                                        const float* __restrict__ bias,
                                        int relu, short8 bf[4], int q) {
#pragma unroll
  for (int ks = 0; ks < 4; ++ks) {
    f32x4 lo = acc[2 * ks], hi = acc[2 * ks + 1];
    if (bias) {
      float4 b0 = *(const float4*)(bias + (2 * ks) * 16 + q * 4);
      float4 b1 = *(const float4*)(bias + (2 * ks + 1) * 16 + q * 4);
      lo[0] += b0.x; lo[1] += b0.y; lo[2] += b0.z; lo[3] += b0.w;
      hi[0] += b1.x; hi[1] += b1.y; hi[2] += b1.z; hi[3] += b1.w;
    }
    if (relu) {
#pragma unroll
      for (int r = 0; r < 4; ++r) {
        lo[r] = fmaxf(lo[r], 0.f); hi[r] = fmaxf(hi[r], 0.f);
      }
    }
    bf[ks] = pkfrag(lo, hi);
  }
}

// ---------------- prep: pi-permuted bf16 weights + fp32 biases ------------
__global__ void __launch_bounds__(256) prep_kernel(
    const float* __restrict__ W1, const float* __restrict__ W2,
    const float* __restrict__ W3, const float* __restrict__ W_comb,
    const float* __restrict__ P, const float* __restrict__ b1,
    const float* __restrict__ b2, const float* __restrict__ b3,
    ushort* __restrict__ ws) {
  int idx = blockIdx.x * 256 + threadIdx.x;
  if (idx < W_ELEMS) {
    float val;
    if (idx < 8192) {
      int p = idx >> 6, k = idx & 63;
      val = W1[piperm(p) * 64 + k];
    } else {
      int r = idx - 8192, m = r >> 14, rr = r & 16383;
      int p = rr >> 7, k = rr & 127, pp = piperm(p);
      switch (m) {
        case 0:  val = W2[pp * 128 + k]; break;
        case 1:  val = W3[pp * 128 + k]; break;
        case 2:  val = W_comb[pp * 256 + 128 + k]; break;   // Wcr
        case 3:  val = W_comb[pp * 256 + k]; break;         // Wcl
        case 4:  val = P[pp * 128 + k]; break;              // P0
        default: val = P[16384 + pp * 128 + k]; break;      // P1
      }
    }
    ws[idx] = f2bf(val);
  } else if (idx < W_ELEMS + B_ELEMS) {
    int r = idx - W_ELEMS;            // 0..383
    int which = r >> 7, p = r & 127;
    const float* src = (which == 0) ? b1 : ((which == 1) ? b2 : b3);
    ((float*)(ws + OFF_BIAS))[r] = src[piperm(p)];
  }
}

// ---------------- node kernel: hu/hv = h @ Wcl^T (pi-slot storage) --------
// Barrier-free: one wave = 16 nodes. 100000/16 = 6250 waves per half.
__global__ void __launch_bounds__(256, 3) node_kernel(
    const float* __restrict__ h_src, const float* __restrict__ h_dst,
    ushort* __restrict__ ws) {
  const int tid = threadIdx.x, wv = tid >> 6, lane = tid & 63;
  const int l15 = lane & 15, q = lane >> 4;
  long gid = (long)blockIdx.x * 4 + wv;
  const float* h; ushort* op; long n_base;
  if (gid < 6250) { h = h_src; op = ws + OFF_HU; n_base = gid * 16; }
  else            { h = h_dst; op = ws + OFF_HV; n_base = (gid - 6250) * 16; }
  const long node = n_base + l15;     // exact fit, no OOB

  short8 bx[4];
#pragma unroll
  for (int ks = 0; ks < 4; ++ks) {
    const float* sp = h + node * 128 + ks * 32 + q * 8;
    float4 x0 = *(const float4*)sp, x1 = *(const float4*)(sp + 4);
    bx[ks] = pkfrag((f32x4){x0.x, x0.y, x0.z, x0.w},
                    (f32x4){x1.x, x1.y, x1.z, x1.w});
  }
  f32x4 acc[8];
  zero8(acc);
  gemmW<4>(ws + OFF_WCL, 128, bx, acc, l15, q);
#pragma unroll
  for (int mt = 0; mt < 8; ++mt) {
    ushort2 a = pk2(acc[mt][0], acc[mt][1]);
    ushort2 b = pk2(acc[mt][2], acc[mt][3]);
    ushort4 o; o.x = a.x; o.y = a.y; o.z = b.x; o.w = b.y;
    *(ushort4*)(op + node * 128 + mt * 16 + q * 4) = o;
  }
}

// ---------------- fused edge kernel: barrier-free, wave = 16 edges --------
__global__ void __launch_bounds__(256, 3) edge_kernel(
    const float* __restrict__ efeats, const int* __restrict__ u_idx,
    const int* __restrict__ v_idx, const float* __restrict__ W_cb,
    const ushort* __restrict__ ws, float* __restrict__ out) {
  const int tid = threadIdx.x, wv = tid >> 6, lane = tid & 63;
  const int l15 = lane & 15, q = lane >> 4;
  const float* biasp = (const float*)(ws + OFF_BIAS);
  const long e_base = ((long)blockIdx.x * 4 + wv) * 16;
  long eidx = e_base + l15;
  if (eidx >= EDG) eidx = EDG - 1;
  const int vi = v_idx[eidx], ui = u_idx[eidx];

  // X B-frags straight from global (K=64, natural k-order)
  short8 bx[2];
#pragma unroll
  for (int ks = 0; ks < 2; ++ks) {
    const float* sp = efeats + eidx * 64 + ks * 32 + q * 8;
    float4 x0 = *(const float4*)sp, x1 = *(const float4*)(sp + 4);
    bx[ks] = pkfrag((f32x4){x0.x, x0.y, x0.z, x0.w},
                    (f32x4){x1.x, x1.y, x1.z, x1.w});
  }

  f32x4 acc[8];
  short8 f[4];
  // e1 = relu(X@W1^T + b1)
  zero8(acc);
#pragma unroll
  for (int ks = 0; ks < 2; ++ks)
#pragma unroll
    for (int mt = 0; mt < 8; ++mt) {
      short8 a = *(const short8*)(ws + OFF_W1 + (mt * 16 + l15) * 64 + ks * 32 + q * 8);
      acc[mt] = __builtin_amdgcn_mfma_f32_16x16x32_bf16(a, bx[ks], acc[mt], 0, 0, 0);
    }
  mkfrags(acc, biasp, 1, f, q);
  // e2 = relu(e1@W2^T + b2)
  zero8(acc); gemmW<4>(ws + OFF_W2, 128, f, acc, l15, q);
  mkfrags(acc, biasp + 128, 1, f, q);
  // e3 = e2@W3^T + b3
  zero8(acc); gemmW<4>(ws + OFF_W3, 128, f, acc, l15, q);
  mkfrags(acc, biasp + 256, 0, f, q);
  // ec = e3@Wcr^T (kept fp32 in acc)
  f32x4 ec[8];
  zero8(ec); gemmW<4>(ws + OFF_WCR, 128, f, ec, l15, q);

  // V frags (bf16) = hv[vi] + ec ; U (fp32, acc layout) = hu[ui] + ec
  const ushort* hvrow = ws + OFF_HV + (long)vi * 128;
  const ushort* hurow = ws + OFF_HU + (long)ui * 128;
  short8 V[4];
#pragma unroll
  for (int ks = 0; ks < 4; ++ks) {
    ushort4 h0 = *(const ushort4*)(hvrow + (2 * ks) * 16 + q * 4);
    ushort4 h1 = *(const ushort4*)(hvrow + (2 * ks + 1) * 16 + q * 4);
    f32x4 lo, hi;
    lo[0] = bf2f(h0.x) + ec[2 * ks][0];     lo[1] = bf2f(h0.y) + ec[2 * ks][1];
    lo[2] = bf2f(h0.z) + ec[2 * ks][2];     lo[3] = bf2f(h0.w) + ec[2 * ks][3];
    hi[0] = bf2f(h1.x) + ec[2 * ks + 1][0]; hi[1] = bf2f(h1.y) + ec[2 * ks + 1][1];
    hi[2] = bf2f(h1.z) + ec[2 * ks + 1][2]; hi[3] = bf2f(h1.w) + ec[2 * ks + 1][3];
    V[ks] = pkfrag(lo, hi);
  }
  f32x4 Ufp[8];
#pragma unroll
  for (int mt = 0; mt < 8; ++mt) {
    ushort4 h = *(const ushort4*)(hurow + mt * 16 + q * 4);
    Ufp[mt][0] = bf2f(h.x) + ec[mt][0];
    Ufp[mt][1] = bf2f(h.y) + ec[mt][1];
    Ufp[mt][2] = bf2f(h.z) + ec[mt][2];
    Ufp[mt][3] = bf2f(h.w) + ec[mt][3];
  }

  // bilinear: per mt-tile compute T0/T1 then dot with U immediately
  float pb0 = 0.f, pb1 = 0.f;
#pragma unroll
  for (int mt = 0; mt < 8; ++mt) {
    f32x4 t0 = {0.f, 0.f, 0.f, 0.f}, t1 = {0.f, 0.f, 0.f, 0.f};
#pragma unroll
    for (int ks = 0; ks < 4; ++ks) {
      short8 a0 = *(const short8*)(ws + OFF_P0 + (mt * 16 + l15) * 128 + ks * 32 + q * 8);
      short8 a1 = *(const short8*)(ws + OFF_P1 + (mt * 16 + l15) * 128 + ks * 32 + q * 8);
      t0 = __builtin_amdgcn_mfma_f32_16x16x32_bf16(a0, V[ks], t0, 0, 0, 0);
      t1 = __builtin_amdgcn_mfma_f32_16x16x32_bf16(a1, V[ks], t1, 0, 0, 0);
    }
    pb0 += t0[0] * Ufp[mt][0] + t0[1] * Ufp[mt][1] + t0[2] * Ufp[mt][2] + t0[3] * Ufp[mt][3];
    pb1 += t1[0] * Ufp[mt][0] + t1[1] * Ufp[mt][1] + t1[2] * Ufp[mt][2] + t1[3] * Ufp[mt][3];
  }
  // quad-reduce (feat halves live in the 4 quads)
  pb0 += __shfl_xor(pb0, 16, 64); pb0 += __shfl_xor(pb0, 32, 64);
  pb1 += __shfl_xor(pb1, 16, 64); pb1 += __shfl_xor(pb1, 32, 64);

  // epilogue: lane (q,l15) writes class q of its edge; q==0 also class 4
  if (e_base + l15 < EDG) {
    long o = (e_base + l15) * NCLS;
    out[o + q] = pb0 * W_cb[q * 2] + pb1 * W_cb[q * 2 + 1];
    if (q == 0) out[o + 4] = pb0 * W_cb[8] + pb1 * W_cb[9];
  }
}

extern "C" void kernel_launch(void* const* d_in, const int* in_sizes, int n_in,
                              void* d_out, int out_size, void* d_ws,
                              size_t ws_size, hipStream_t stream) {
  const float* h_src  = (const float*)d_in[0];
  const float* h_dst  = (const float*)d_in[1];
  const float* efeats = (const float*)d_in[2];
  const int*   u_idx  = (const int*)d_in[3];
  const int*   v_idx  = (const int*)d_in[4];
  const float* W1     = (const float*)d_in[5];
  const float* b1     = (const float*)d_in[6];
  const float* W2     = (const float*)d_in[7];
  const float* b2     = (const float*)d_in[8];
  const float* W3     = (const float*)d_in[9];
  const float* b3     = (const float*)d_in[10];
  const float* W_comb = (const float*)d_in[11];
  const float* P      = (const float*)d_in[12];
  const float* W_cb   = (const float*)d_in[13];
  ushort* ws = (ushort*)d_ws;
  float* out = (float*)d_out;

  prep_kernel<<<(W_ELEMS + B_ELEMS + 255) / 256, 256, 0, stream>>>(
      W1, W2, W3, W_comb, P, b1, b2, b3, ws);
  // 2*6250 waves / 4 per block
  node_kernel<<<3125, 256, 0, stream>>>(h_src, h_dst, ws);
  // 31250 waves / 4 per block
  edge_kernel<<<(EDG / 16 + 3) / 4 + 1, 256, 0, stream>>>(
      efeats, u_idx, v_idx, W_cb, ws, out);
}